// Round 10
// baseline (1198.185 us; speedup 1.0000x reference)
//
#include <hip/hip_runtime.h>
#include <hip/hip_cooperative_groups.h>

namespace cg = cooperative_groups;

#define LEAKY_SLOPE 0.2f

constexpr int B_   = 16;
constexpr int N_   = 4096;
constexpr int K_   = 4096;
constexpr int IN_  = 16384;   // K + 3K
constexpr int H1_  = 1024;
constexpr int H2_  = 512;
constexpr int OUT_ = 256;

constexpr int NCH = 32;
constexpr int NPC = N_ / NCH;   // 128
constexpr int KPT = 8;
constexpr int KTB = 256 * KPT;  // 2048

// =========================================================================
// Cooperative mega-kernel: 1024 blocks x 256 threads, 6 phases with
// grid.sync() between. LDS = 2KB (pts) + 8.7KB (red) = 10.75KB -> >=4
// blocks/CU under any occupancy model; __launch_bounds__(256,4) caps VGPR
// at 128 -> 4 blocks/CU -> 1024 co-resident exactly. Kills ~7 inter-
// dispatch gaps (the measured ~100us hole in r4-r8 budgets).
// =========================================================================
__global__ __launch_bounds__(256, 4) void mega(
    const float* __restrict__ pc, const float* __restrict__ basis,
    const float* __restrict__ W1, const float* __restrict__ b1,
    const float* __restrict__ W2, const float* __restrict__ b2,
    const float* __restrict__ W3, const float* __restrict__ b3,
    float* __restrict__ gfeat, float* __restrict__ bps,
    unsigned long long* __restrict__ part_enc, float* __restrict__ partial,
    float* __restrict__ h1T, float* __restrict__ h2T)
{
#pragma clang fp contract(off)
    cg::grid_group grid = cg::this_grid();
    __shared__ float4 pts[NPC];        // 2 KB    (phase A)
    __shared__ float  red[2][64][17];  // 8.7 KB  (phases E/F)

    const int tid = (int)threadIdx.x;
    const int bx  = (int)blockIdx.x;

    // ---- Phase A: partial argmin per (k-tile, batch, n-chunk) ------------
    // e2 = pn - 2*cross (bn constant in argmin over n; validated r3-r8).
    // Plain u64 key store per chunk: key = mapped_e2<<32 | n (r7-proven).
    {
        const int kt = bx & 1;
        const int b  = (bx >> 1) & 15;
        const int c  = bx >> 5;         // [0,32)
        const int n0 = c * NPC;

        if (tid < NPC) {
            const float* pp = pc + ((size_t)b * N_ + n0 + tid) * 3;
            float x = pp[0], y = pp[1], z = pp[2];
            pts[tid] = make_float4(x, y, z, (x * x + y * y) + z * z); // numpy order
        }
        __syncthreads();

        const int k0 = kt * KTB + tid;
        float nbx[KPT], nby[KPT], nbz[KPT], best[KPT];
        int   bi[KPT];
#pragma unroll
        for (int q = 0; q < KPT; ++q) {
            int k = k0 + q * 256;
            nbx[q] = -2.0f * basis[k * 3 + 0];
            nby[q] = -2.0f * basis[k * 3 + 1];
            nbz[q] = -2.0f * basis[k * 3 + 2];
            best[q] = 3.4028235e38f;
            bi[q] = 0;
        }

#pragma unroll 2
        for (int n = 0; n < NPC; ++n) {
            float4 p = pts[n];
#pragma unroll
            for (int q = 0; q < KPT; ++q) {
                float e2 = __builtin_fmaf(nbx[q], p.x,
                            __builtin_fmaf(nby[q], p.y,
                             __builtin_fmaf(nbz[q], p.z, p.w)));
                if (e2 < best[q]) { best[q] = e2; bi[q] = n0 + n; }  // strict <
            }
        }

#pragma unroll
        for (int q = 0; q < KPT; ++q) {
            unsigned u = __float_as_uint(best[q]);
            u = (u & 0x80000000u) ? ~u : (u | 0x80000000u);   // monotone map
            unsigned long long v = ((unsigned long long)u << 32) | (unsigned)bi[q];
            part_enc[(size_t)c * (B_ * K_) + b * K_ + (k0 + q * 256)] = v;
        }
    }
    __threadfence();
    grid.sync();

    // ---- Phase B: fold 32 chunk keys (u64 < = lex (e2,n) -> first-min),
    // gather nearest point, write bps feature row --------------------------
    if (bx < 256) {
        const int t = bx * 256 + tid;
        const int b = t >> 12;
        const int k = t & (K_ - 1);

        unsigned long long bestk = part_enc[t];
#pragma unroll 8
        for (int c = 1; c < NCH; ++c) {
            unsigned long long v = part_enc[(size_t)c * (B_ * K_) + t];
            if (v < bestk) bestk = v;
        }
        const int bi = (int)(unsigned)(bestk & 0xffffffffull);

        const float* p = pc + ((size_t)b * N_ + bi) * 3;
        float dx = p[0] - basis[k * 3 + 0];
        float dy = p[1] - basis[k * 3 + 1];
        float dz = p[2] - basis[k * 3 + 2];
        float dist = sqrtf((dx * dx + dy * dy) + dz * dz);

        float* row = bps + (size_t)b * IN_;
        row[k]              = dist;
        row[K_ + 3 * k + 0] = dx;
        row[K_ + 3 * k + 1] = dy;
        row[K_ + 3 * k + 2] = dz;
    }
    __threadfence();
    grid.sync();

    // ---- Phase C: L1 GEMM [16,16384]@[16384,1024] ------------------------
    // 4 colblocks x 256 k-chunks (ILEN=64); wave -> 4 batches (scalar A
    // streams), lane -> 4 cols (float4 W1 load, 1KB/wave).
    {
        const int lane = tid & 63;
        const int wg   = __builtin_amdgcn_readfirstlane(tid >> 6);
        const int cb   = bx & 3;
        const int ch   = bx >> 2;       // [0,256)
        const int j0   = cb * 256 + lane * 4;
        const int i0   = ch * 64;

        const float* A0 = bps + (size_t)(4 * wg + 0) * IN_ + i0;
        const float* A1 = bps + (size_t)(4 * wg + 1) * IN_ + i0;
        const float* A2 = bps + (size_t)(4 * wg + 2) * IN_ + i0;
        const float* A3 = bps + (size_t)(4 * wg + 3) * IN_ + i0;

        float4 acc0 = {0,0,0,0}, acc1 = {0,0,0,0}, acc2 = {0,0,0,0}, acc3 = {0,0,0,0};

#pragma unroll 8
        for (int i = 0; i < 64; ++i) {
            float4 wv = *(const float4*)(W1 + (size_t)(i0 + i) * H1_ + j0);
            float a0 = A0[i], a1 = A1[i], a2 = A2[i], a3 = A3[i];
            acc0.x = __builtin_fmaf(a0, wv.x, acc0.x);
            acc0.y = __builtin_fmaf(a0, wv.y, acc0.y);
            acc0.z = __builtin_fmaf(a0, wv.z, acc0.z);
            acc0.w = __builtin_fmaf(a0, wv.w, acc0.w);
            acc1.x = __builtin_fmaf(a1, wv.x, acc1.x);
            acc1.y = __builtin_fmaf(a1, wv.y, acc1.y);
            acc1.z = __builtin_fmaf(a1, wv.z, acc1.z);
            acc1.w = __builtin_fmaf(a1, wv.w, acc1.w);
            acc2.x = __builtin_fmaf(a2, wv.x, acc2.x);
            acc2.y = __builtin_fmaf(a2, wv.y, acc2.y);
            acc2.z = __builtin_fmaf(a2, wv.z, acc2.z);
            acc2.w = __builtin_fmaf(a2, wv.w, acc2.w);
            acc3.x = __builtin_fmaf(a3, wv.x, acc3.x);
            acc3.y = __builtin_fmaf(a3, wv.y, acc3.y);
            acc3.z = __builtin_fmaf(a3, wv.z, acc3.z);
            acc3.w = __builtin_fmaf(a3, wv.w, acc3.w);
        }

        float* base = partial + (size_t)ch * 16 * H1_;
        *(float4*)(base + (size_t)(4 * wg + 0) * H1_ + j0) = acc0;
        *(float4*)(base + (size_t)(4 * wg + 1) * H1_ + j0) = acc1;
        *(float4*)(base + (size_t)(4 * wg + 2) * H1_ + j0) = acc2;
        *(float4*)(base + (size_t)(4 * wg + 3) * H1_ + j0) = acc3;
    }
    __threadfence();
    grid.sync();

    // ---- Phase D: reduce 256 chunks + bias + leaky -> h1T[col][16] -------
    if (bx < 64) {
        const int p = bx * 256 + tid;
        float s = 0.0f;
#pragma unroll 8
        for (int c = 0; c < 256; ++c) s += partial[(size_t)c * (16 * H1_) + p];
        const int col = p & (H1_ - 1);
        const int b   = p >> 10;
        s += b1[col];
        s = fmaxf(s, LEAKY_SLOPE * s);
        h1T[(size_t)col * 16 + b] = s;
    }
    __threadfence();
    grid.sync();

    // ---- Phase E: L2 [16,1024]@[1024,512] + bias + leaky -> h2T ----------
    if (bx < 8) {
        const int lane = tid & 63;
        const int w    = __builtin_amdgcn_readfirstlane(tid >> 6);
        const int j    = bx * 64 + lane;
        const int i0   = w * 256;

        float acc[16];
#pragma unroll
        for (int r = 0; r < 16; ++r) acc[r] = 0.0f;

#pragma unroll 4
        for (int i = i0; i < i0 + 256; ++i) {
            float wv = W2[(size_t)i * H2_ + j];
            const float4* Ar = (const float4*)(h1T + (size_t)i * 16);
            float4 q0 = Ar[0], q1 = Ar[1], q2 = Ar[2], q3 = Ar[3];
            acc[0]  = __builtin_fmaf(q0.x, wv, acc[0]);
            acc[1]  = __builtin_fmaf(q0.y, wv, acc[1]);
            acc[2]  = __builtin_fmaf(q0.z, wv, acc[2]);
            acc[3]  = __builtin_fmaf(q0.w, wv, acc[3]);
            acc[4]  = __builtin_fmaf(q1.x, wv, acc[4]);
            acc[5]  = __builtin_fmaf(q1.y, wv, acc[5]);
            acc[6]  = __builtin_fmaf(q1.z, wv, acc[6]);
            acc[7]  = __builtin_fmaf(q1.w, wv, acc[7]);
            acc[8]  = __builtin_fmaf(q2.x, wv, acc[8]);
            acc[9]  = __builtin_fmaf(q2.y, wv, acc[9]);
            acc[10] = __builtin_fmaf(q2.z, wv, acc[10]);
            acc[11] = __builtin_fmaf(q2.w, wv, acc[11]);
            acc[12] = __builtin_fmaf(q3.x, wv, acc[12]);
            acc[13] = __builtin_fmaf(q3.y, wv, acc[13]);
            acc[14] = __builtin_fmaf(q3.z, wv, acc[14]);
            acc[15] = __builtin_fmaf(q3.w, wv, acc[15]);
        }

        if (w < 2) {
#pragma unroll
            for (int r = 0; r < 16; ++r) red[w][lane][r] = acc[r];
        }
        __syncthreads();
        if (w >= 2) {
#pragma unroll
            for (int r = 0; r < 16; ++r) red[w - 2][lane][r] += acc[r];
        }
        __syncthreads();

#pragma unroll
        for (int e = 0; e < 4; ++e) {
            int p  = tid * 4 + e;       // col_local*16 + batch
            int cl = p >> 4;
            int bt = p & 15;
            float s = b2[bx * 64 + cl] + red[0][cl][bt] + red[1][cl][bt];
            s = fmaxf(s, LEAKY_SLOPE * s);
            h2T[((size_t)bx * 64 + cl) * 16 + bt] = s;
        }
    }
    __threadfence();
    grid.sync();

    // ---- Phase F: L3 [16,512]@[512,256] + bias -> gfeat ------------------
    if (bx < 4) {
        const int lane = tid & 63;
        const int w    = __builtin_amdgcn_readfirstlane(tid >> 6);
        const int j    = bx * 64 + lane;
        const int i0   = w * 128;

        float acc[16];
#pragma unroll
        for (int r = 0; r < 16; ++r) acc[r] = 0.0f;

#pragma unroll 4
        for (int i = i0; i < i0 + 128; ++i) {
            float wv = W3[(size_t)i * OUT_ + j];
            const float4* Ar = (const float4*)(h2T + (size_t)i * 16);
            float4 q0 = Ar[0], q1 = Ar[1], q2 = Ar[2], q3 = Ar[3];
            acc[0]  = __builtin_fmaf(q0.x, wv, acc[0]);
            acc[1]  = __builtin_fmaf(q0.y, wv, acc[1]);
            acc[2]  = __builtin_fmaf(q0.z, wv, acc[2]);
            acc[3]  = __builtin_fmaf(q0.w, wv, acc[3]);
            acc[4]  = __builtin_fmaf(q1.x, wv, acc[4]);
            acc[5]  = __builtin_fmaf(q1.y, wv, acc[5]);
            acc[6]  = __builtin_fmaf(q1.z, wv, acc[6]);
            acc[7]  = __builtin_fmaf(q1.w, wv, acc[7]);
            acc[8]  = __builtin_fmaf(q2.x, wv, acc[8]);
            acc[9]  = __builtin_fmaf(q2.y, wv, acc[9]);
            acc[10] = __builtin_fmaf(q2.z, wv, acc[10]);
            acc[11] = __builtin_fmaf(q2.w, wv, acc[11]);
            acc[12] = __builtin_fmaf(q3.x, wv, acc[12]);
            acc[13] = __builtin_fmaf(q3.y, wv, acc[13]);
            acc[14] = __builtin_fmaf(q3.z, wv, acc[14]);
            acc[15] = __builtin_fmaf(q3.w, wv, acc[15]);
        }

        if (w < 2) {
#pragma unroll
            for (int r = 0; r < 16; ++r) red[w][lane][r] = acc[r];
        }
        __syncthreads();
        if (w >= 2) {
#pragma unroll
            for (int r = 0; r < 16; ++r) red[w - 2][lane][r] += acc[r];
        }
        __syncthreads();

#pragma unroll
        for (int e = 0; e < 4; ++e) {
            int p  = tid * 4 + e;
            int cl = p >> 4;
            int bt = p & 15;
            float s = b3[bx * 64 + cl] + red[0][cl][bt] + red[1][cl][bt];
            gfeat[(size_t)bt * OUT_ + bx * 64 + cl] = s;
        }
    }
}

// =========================================================================
// Fallback path: the r8-proven 8-dispatch pipeline (213us), used only if
// the cooperative launch is rejected by the runtime.
// =========================================================================
__global__ __launch_bounds__(256) void enc_partial_fb(
    const float* __restrict__ pc, const float* __restrict__ basis,
    unsigned long long* __restrict__ packed)
{
#pragma clang fp contract(off)
    __shared__ float4 pts[NPC];
    const int kt = blockIdx.x;
    const int b  = blockIdx.y;
    const int c  = blockIdx.z;
    const int n0 = c * NPC;

    if (threadIdx.x < NPC) {
        const float* pp = pc + ((size_t)b * N_ + n0 + threadIdx.x) * 3;
        float x = pp[0], y = pp[1], z = pp[2];
        pts[threadIdx.x] = make_float4(x, y, z, (x * x + y * y) + z * z);
    }
    __syncthreads();

    const int k0 = kt * KTB + (int)threadIdx.x;
    float nbx[KPT], nby[KPT], nbz[KPT], best[KPT];
    int   bi[KPT];
#pragma unroll
    for (int q = 0; q < KPT; ++q) {
        int k = k0 + q * 256;
        nbx[q] = -2.0f * basis[k * 3 + 0];
        nby[q] = -2.0f * basis[k * 3 + 1];
        nbz[q] = -2.0f * basis[k * 3 + 2];
        best[q] = 3.4028235e38f;
        bi[q] = 0;
    }
#pragma unroll 2
    for (int n = 0; n < NPC; ++n) {
        float4 p = pts[n];
#pragma unroll
        for (int q = 0; q < KPT; ++q) {
            float e2 = __builtin_fmaf(nbx[q], p.x,
                        __builtin_fmaf(nby[q], p.y,
                         __builtin_fmaf(nbz[q], p.z, p.w)));
            if (e2 < best[q]) { best[q] = e2; bi[q] = n0 + n; }
        }
    }
#pragma unroll
    for (int q = 0; q < KPT; ++q) {
        unsigned u = __float_as_uint(best[q]);
        u = (u & 0x80000000u) ? ~u : (u | 0x80000000u);
        unsigned long long v = ((unsigned long long)u << 32) | (unsigned)bi[q];
        atomicMin(&packed[(size_t)b * K_ + (k0 + q * 256)], v);
    }
}

__global__ __launch_bounds__(256) void enc_finish_fb(
    const float* __restrict__ pc, const float* __restrict__ basis,
    const unsigned long long* __restrict__ packed, float* __restrict__ bps_out)
{
#pragma clang fp contract(off)
    const int t = blockIdx.x * 256 + (int)threadIdx.x;
    const int b = t >> 12;
    const int k = t & (K_ - 1);
    const int bi = (int)(unsigned)(packed[t] & 0xffffffffull);
    const float* p = pc + ((size_t)b * N_ + bi) * 3;
    float dx = p[0] - basis[k * 3 + 0];
    float dy = p[1] - basis[k * 3 + 1];
    float dz = p[2] - basis[k * 3 + 2];
    float dist = sqrtf((dx * dx + dy * dy) + dz * dz);
    float* row = bps_out + (size_t)b * IN_;
    row[k]              = dist;
    row[K_ + 3 * k + 0] = dx;
    row[K_ + 3 * k + 1] = dy;
    row[K_ + 3 * k + 2] = dz;
}

__global__ __launch_bounds__(256) void gemm1_fb(
    const float* __restrict__ A, const float* __restrict__ W,
    float* __restrict__ part)
{
    const int lane = (int)threadIdx.x & 63;
    const int wg   = __builtin_amdgcn_readfirstlane((int)threadIdx.x >> 6);
    const int j0   = blockIdx.x * 256 + lane * 4;
    const int i0   = blockIdx.y * 128;

    const float* A0 = A + (size_t)(4 * wg + 0) * IN_ + i0;
    const float* A1 = A + (size_t)(4 * wg + 1) * IN_ + i0;
    const float* A2 = A + (size_t)(4 * wg + 2) * IN_ + i0;
    const float* A3 = A + (size_t)(4 * wg + 3) * IN_ + i0;

    float4 acc0 = {0,0,0,0}, acc1 = {0,0,0,0}, acc2 = {0,0,0,0}, acc3 = {0,0,0,0};
#pragma unroll 8
    for (int i = 0; i < 128; ++i) {
        float4 wv = *(const float4*)(W + (size_t)(i0 + i) * H1_ + j0);
        float a0 = A0[i], a1 = A1[i], a2 = A2[i], a3 = A3[i];
        acc0.x = __builtin_fmaf(a0, wv.x, acc0.x);
        acc0.y = __builtin_fmaf(a0, wv.y, acc0.y);
        acc0.z = __builtin_fmaf(a0, wv.z, acc0.z);
        acc0.w = __builtin_fmaf(a0, wv.w, acc0.w);
        acc1.x = __builtin_fmaf(a1, wv.x, acc1.x);
        acc1.y = __builtin_fmaf(a1, wv.y, acc1.y);
        acc1.z = __builtin_fmaf(a1, wv.z, acc1.z);
        acc1.w = __builtin_fmaf(a1, wv.w, acc1.w);
        acc2.x = __builtin_fmaf(a2, wv.x, acc2.x);
        acc2.y = __builtin_fmaf(a2, wv.y, acc2.y);
        acc2.z = __builtin_fmaf(a2, wv.z, acc2.z);
        acc2.w = __builtin_fmaf(a2, wv.w, acc2.w);
        acc3.x = __builtin_fmaf(a3, wv.x, acc3.x);
        acc3.y = __builtin_fmaf(a3, wv.y, acc3.y);
        acc3.z = __builtin_fmaf(a3, wv.z, acc3.z);
        acc3.w = __builtin_fmaf(a3, wv.w, acc3.w);
    }
    float* base = part + (size_t)blockIdx.y * 16 * H1_;
    *(float4*)(base + (size_t)(4 * wg + 0) * H1_ + j0) = acc0;
    *(float4*)(base + (size_t)(4 * wg + 1) * H1_ + j0) = acc1;
    *(float4*)(base + (size_t)(4 * wg + 2) * H1_ + j0) = acc2;
    *(float4*)(base + (size_t)(4 * wg + 3) * H1_ + j0) = acc3;
}

__global__ __launch_bounds__(256) void reduce_act1_fb(
    const float* __restrict__ part, const float* __restrict__ bias,
    float* __restrict__ outT, int nchunks)
{
    const int p = blockIdx.x * 256 + (int)threadIdx.x;
    float s = 0.0f;
#pragma unroll 8
    for (int c = 0; c < nchunks; ++c) s += part[(size_t)c * (16 * H1_) + p];
    const int col = p & (H1_ - 1);
    const int b   = p >> 10;
    s += bias[col];
    s = fmaxf(s, LEAKY_SLOPE * s);
    outT[(size_t)col * 16 + b] = s;
}

template<int KDIM, int NCOLS>
__global__ __launch_bounds__(512) void gemm_small_fb(
    const float* __restrict__ AT, const float* __restrict__ W,
    const float* __restrict__ bias,
    float* __restrict__ outT, float* __restrict__ out_rm)
{
    __shared__ float red[8][64][17];
    const int lane = (int)threadIdx.x & 63;
    const int w    = __builtin_amdgcn_readfirstlane((int)threadIdx.x >> 6);
    const int j    = blockIdx.x * 64 + lane;
    constexpr int KQ = KDIM / 8;
    const int i0 = w * KQ;

    float acc[16];
#pragma unroll
    for (int r = 0; r < 16; ++r) acc[r] = 0.0f;
#pragma unroll 4
    for (int i = i0; i < i0 + KQ; ++i) {
        float wv = W[(size_t)i * NCOLS + j];
        const float4* Ar = (const float4*)(AT + (size_t)i * 16);
        float4 q0 = Ar[0], q1 = Ar[1], q2 = Ar[2], q3 = Ar[3];
        acc[0]  = __builtin_fmaf(q0.x, wv, acc[0]);
        acc[1]  = __builtin_fmaf(q0.y, wv, acc[1]);
        acc[2]  = __builtin_fmaf(q0.z, wv, acc[2]);
        acc[3]  = __builtin_fmaf(q0.w, wv, acc[3]);
        acc[4]  = __builtin_fmaf(q1.x, wv, acc[4]);
        acc[5]  = __builtin_fmaf(q1.y, wv, acc[5]);
        acc[6]  = __builtin_fmaf(q1.z, wv, acc[6]);
        acc[7]  = __builtin_fmaf(q1.w, wv, acc[7]);
        acc[8]  = __builtin_fmaf(q2.x, wv, acc[8]);
        acc[9]  = __builtin_fmaf(q2.y, wv, acc[9]);
        acc[10] = __builtin_fmaf(q2.z, wv, acc[10]);
        acc[11] = __builtin_fmaf(q2.w, wv, acc[11]);
        acc[12] = __builtin_fmaf(q3.x, wv, acc[12]);
        acc[13] = __builtin_fmaf(q3.y, wv, acc[13]);
        acc[14] = __builtin_fmaf(q3.z, wv, acc[14]);
        acc[15] = __builtin_fmaf(q3.w, wv, acc[15]);
    }
#pragma unroll
    for (int r = 0; r < 16; ++r) red[w][lane][r] = acc[r];
    __syncthreads();
#pragma unroll
    for (int q = 0; q < 2; ++q) {
        int p  = (int)threadIdx.x * 2 + q;
        int cl = p >> 4;
        int bt = p & 15;
        float s = bias[blockIdx.x * 64 + cl];
#pragma unroll
        for (int ww = 0; ww < 8; ++ww) s += red[ww][cl][bt];
        if (outT) {
            s = fmaxf(s, LEAKY_SLOPE * s);
            outT[((size_t)blockIdx.x * 64 + cl) * 16 + bt] = s;
        }
        if (out_rm) out_rm[(size_t)bt * NCOLS + blockIdx.x * 64 + cl] = s;
    }
}

// -------------------------------------------------------------------------
extern "C" void kernel_launch(void* const* d_in, const int* in_sizes, int n_in,
                              void* d_out, int out_size, void* d_ws, size_t ws_size,
                              hipStream_t stream)
{
    const float* pc    = (const float*)d_in[0];
    const float* basis = (const float*)d_in[1];
    const float* W1    = (const float*)d_in[2];
    const float* b1    = (const float*)d_in[3];
    const float* W2    = (const float*)d_in[4];
    const float* b2    = (const float*)d_in[5];
    const float* W3    = (const float*)d_in[6];
    const float* b3    = (const float*)d_in[7];

    float* out   = (float*)d_out;
    float* gfeat = out;                 // [16][256]
    float* bps   = out + B_ * OUT_;     // [16][16384]

    char* ws = (char*)d_ws;
    unsigned long long* part_enc = (unsigned long long*)ws;          // 16MB
    float* partial = (float*)(ws + (size_t)16 * 1024 * 1024);        // 16MB
    float* h1T     = (float*)(ws + (size_t)32 * 1024 * 1024);        // 64KB
    float* h2T     = (float*)(ws + (size_t)32 * 1024 * 1024 + 64 * 1024); // 32KB

    void* args[14] = {
        (void*)&pc, (void*)&basis, (void*)&W1, (void*)&b1,
        (void*)&W2, (void*)&b2, (void*)&W3, (void*)&b3,
        (void*)&gfeat, (void*)&bps, (void*)&part_enc, (void*)&partial,
        (void*)&h1T, (void*)&h2T
    };
    hipError_t err = hipLaunchCooperativeKernel(
        mega, dim3(1024), dim3(256), args, 0, stream);

    if (err != hipSuccess) {
        // deterministic fallback: r8-proven 8-dispatch pipeline
        unsigned long long* packed = part_enc;   // 512KB region reuse
        hipMemsetAsync(packed, 0xFF, (size_t)B_ * K_ * 8, stream);
        enc_partial_fb<<<dim3(K_ / KTB, B_, NCH), 256, 0, stream>>>(pc, basis, packed);
        enc_finish_fb<<<(B_ * K_) / 256, 256, 0, stream>>>(pc, basis, packed, bps);
        gemm1_fb<<<dim3(4, 128), 256, 0, stream>>>(bps, W1, partial);
        reduce_act1_fb<<<(H1_ * 16) / 256, 256, 0, stream>>>(partial, b1, h1T, 128);
        gemm_small_fb<1024, H2_><<<8, 512, 0, stream>>>(h1T, W2, b2, h2T, nullptr);
        gemm_small_fb<512, OUT_><<<4, 512, 0, stream>>>(h2T, W3, b3, nullptr, gfeat);
    }
}

// Round 11
// 685.315 us; speedup vs baseline: 1.7484x; 1.7484x over previous
//
#include <hip/hip_runtime.h>

#define LEAKY_SLOPE 0.2f
#define MAGIC 0x0DDF00D5u

constexpr int B_   = 16;
constexpr int N_   = 4096;
constexpr int K_   = 4096;
constexpr int IN_  = 16384;   // K + 3K
constexpr int H1_  = 1024;
constexpr int H2_  = 512;
constexpr int OUT_ = 256;

constexpr int NCH = 32;
constexpr int NPC = N_ / NCH;   // 128
constexpr int KPT = 8;
constexpr int KTB = 2048;

constexpr int NB_A = 1024;      // A & C workers: blocks 0..1023
constexpr int NB_B = 256;       // B workers: blocks 0..255
constexpr int NB_D = 64;        // blocks 1024..1087
constexpr int NB_E = 8;         // blocks 1088..1095
constexpr int NB_F = 4;         // blocks 1096..1099 (1099 = aggregator)
constexpr int NBLK = NB_A + NB_D + NB_E + NB_F;   // 1100

// ---- agent-scope (cache-bypassing) access helpers -----------------------
__device__ __forceinline__ float ldf(const float* p) {
    return __hip_atomic_load(p, __ATOMIC_RELAXED, __HIP_MEMORY_SCOPE_AGENT);
}
__device__ __forceinline__ void stf(float* p, float v) {
    __hip_atomic_store(p, v, __ATOMIC_RELAXED, __HIP_MEMORY_SCOPE_AGENT);
}
__device__ __forceinline__ unsigned long long ldu(const unsigned long long* p) {
    return __hip_atomic_load(p, __ATOMIC_RELAXED, __HIP_MEMORY_SCOPE_AGENT);
}
__device__ __forceinline__ void stu(unsigned long long* p, unsigned long long v) {
    __hip_atomic_store(p, v, __ATOMIC_RELAXED, __HIP_MEMORY_SCOPE_AGENT);
}

// producer: all block stores drained (syncthreads waits vmcnt(0)), then flag
__device__ __forceinline__ void post_flag(unsigned* f) {
    __syncthreads();
    if (threadIdx.x == 0)
        __hip_atomic_store(f, MAGIC, __ATOMIC_RELEASE, __HIP_MEMORY_SCOPE_AGENT);
}
// consumer: poll a single done-word
__device__ __forceinline__ void wait_word(unsigned* w) {
    if (threadIdx.x == 0) {
        while (__hip_atomic_load(w, __ATOMIC_ACQUIRE, __HIP_MEMORY_SCOPE_AGENT) != MAGIC)
            __builtin_amdgcn_s_sleep(8);
    }
    __syncthreads();
}
// aggregator: poll n flags, then publish done-word
__device__ __forceinline__ void aggregate(unsigned* flags, int n, unsigned* done) {
    bool all = false;
    while (!all) {
        bool mine = true;
        for (int i = (int)threadIdx.x; i < n; i += 256)
            mine &= (__hip_atomic_load(&flags[i], __ATOMIC_ACQUIRE,
                                       __HIP_MEMORY_SCOPE_AGENT) == MAGIC);
        all = (bool)__syncthreads_and((int)mine);
        if (!all) __builtin_amdgcn_s_sleep(4);
    }
    if (threadIdx.x == 0)
        __hip_atomic_store(done, MAGIC, __ATOMIC_RELEASE, __HIP_MEMORY_SCOPE_AGENT);
}

// =========================================================================
// Single-dispatch pipeline. Phase bodies are the r8/r10-verified code;
// cross-phase data via agent-scope bypass loads/stores (coherence by
// construction); phase ordering via flags + aggregator (no grid barrier).
// =========================================================================
__global__ __launch_bounds__(256, 5) void pipeline(
    const float* __restrict__ pc, const float* __restrict__ basis,
    const float* __restrict__ W1, const float* __restrict__ b1,
    const float* __restrict__ W2, const float* __restrict__ b2,
    const float* __restrict__ W3, const float* __restrict__ b3,
    float* __restrict__ gfeat, float* __restrict__ bps,
    unsigned long long* __restrict__ part_enc, float* __restrict__ partial,
    float* __restrict__ h1T, float* __restrict__ h2T,
    unsigned* __restrict__ flags)
{
#pragma clang fp contract(off)
    __shared__ float4 pts[NPC];        // 2 KB   (A)
    __shared__ float  stage[2048];     // 8 KB   (C: first 1024; E/F: full)
    __shared__ float  red[2][64][17];  // 8.7 KB (E/F)

    unsigned* fA   = flags;            // 1024
    unsigned* fB   = fA + 1024;        // 256
    unsigned* fC   = fB + 256;         // 1024
    unsigned* fD   = fC + 1024;        // 64
    unsigned* fE   = fD + 64;          // 8
    unsigned* done = fE + 8;           // done[0..4] = A..E

    const int tid = (int)threadIdx.x;
    const int bx  = (int)blockIdx.x;

    if (bx < NB_A) {
        // ---- Phase A: partial argmin per (kt, b, n-chunk) ----------------
        {
            const int kt = bx & 1;
            const int b  = (bx >> 1) & 15;
            const int c  = bx >> 5;
            const int n0 = c * NPC;

            if (tid < NPC) {
                const float* pp = pc + ((size_t)b * N_ + n0 + tid) * 3;
                float x = pp[0], y = pp[1], z = pp[2];
                pts[tid] = make_float4(x, y, z, (x * x + y * y) + z * z);
            }
            __syncthreads();

            const int k0 = kt * KTB + tid;
            float nbx[KPT], nby[KPT], nbz[KPT], best[KPT];
            int   bi[KPT];
#pragma unroll
            for (int q = 0; q < KPT; ++q) {
                int k = k0 + q * 256;
                nbx[q] = -2.0f * basis[k * 3 + 0];
                nby[q] = -2.0f * basis[k * 3 + 1];
                nbz[q] = -2.0f * basis[k * 3 + 2];
                best[q] = 3.4028235e38f;
                bi[q] = 0;
            }
#pragma unroll 2
            for (int n = 0; n < NPC; ++n) {
                float4 p = pts[n];
#pragma unroll
                for (int q = 0; q < KPT; ++q) {
                    float e2 = __builtin_fmaf(nbx[q], p.x,
                                __builtin_fmaf(nby[q], p.y,
                                 __builtin_fmaf(nbz[q], p.z, p.w)));
                    if (e2 < best[q]) { best[q] = e2; bi[q] = n0 + n; }  // strict <
                }
            }
#pragma unroll
            for (int q = 0; q < KPT; ++q) {
                unsigned u = __float_as_uint(best[q]);
                u = (u & 0x80000000u) ? ~u : (u | 0x80000000u);   // monotone map
                unsigned long long v = ((unsigned long long)u << 32) | (unsigned)bi[q];
                stu(&part_enc[(size_t)c * (B_ * K_) + b * K_ + (k0 + q * 256)], v);
            }
        }
        post_flag(&fA[bx]);

        // ---- Phase B (blocks 0..255): fold chunks, gather, write bps -----
        if (bx < NB_B) {
            wait_word(&done[0]);
            const int t = bx * 256 + tid;
            const int b = t >> 12;
            const int k = t & (K_ - 1);

            unsigned long long bestk = ldu(&part_enc[t]);
#pragma unroll 8
            for (int c = 1; c < NCH; ++c) {
                unsigned long long v = ldu(&part_enc[(size_t)c * (B_ * K_) + t]);
                if (v < bestk) bestk = v;   // u64 < = lex (e2, n) -> first-min
            }
            const int bi = (int)(unsigned)(bestk & 0xffffffffull);

            const float* p = pc + ((size_t)b * N_ + bi) * 3;
            float dx = p[0] - basis[k * 3 + 0];
            float dy = p[1] - basis[k * 3 + 1];
            float dz = p[2] - basis[k * 3 + 2];
            float dist = sqrtf((dx * dx + dy * dy) + dz * dz);

            float* row = bps + (size_t)b * IN_;
            stf(&row[k], dist);
            stf(&row[K_ + 3 * k + 0], dx);
            stf(&row[K_ + 3 * k + 1], dy);
            stf(&row[K_ + 3 * k + 2], dz);
            post_flag(&fB[bx]);
        }

        // ---- Phase C: L1 GEMM, 4 colblocks x 256 k-chunks (ILEN=64) ------
        wait_word(&done[1]);
        {
            const int lane = tid & 63;
            const int wg   = tid >> 6;
            const int cb   = bx & 3;
            const int ch   = bx >> 2;       // [0,256)
            const int j0   = cb * 256 + lane * 4;
            const int i0   = ch * 64;

            // stage A-slice [16 rows][64 cols] via per-lane bypass loads
#pragma unroll
            for (int j = 0; j < 4; ++j) {
                int e = tid * 4 + j;                   // [0,1024)
                int row = e >> 6, col = e & 63;
                stage[e] = ldf(&bps[(size_t)row * IN_ + i0 + col]);
            }
            __syncthreads();

            float4 acc0 = {0,0,0,0}, acc1 = {0,0,0,0}, acc2 = {0,0,0,0}, acc3 = {0,0,0,0};
#pragma unroll 8
            for (int i = 0; i < 64; ++i) {
                float4 wv = *(const float4*)(W1 + (size_t)(i0 + i) * H1_ + j0);
                float a0 = stage[(4 * wg + 0) * 64 + i];
                float a1 = stage[(4 * wg + 1) * 64 + i];
                float a2 = stage[(4 * wg + 2) * 64 + i];
                float a3 = stage[(4 * wg + 3) * 64 + i];
                acc0.x = __builtin_fmaf(a0, wv.x, acc0.x);
                acc0.y = __builtin_fmaf(a0, wv.y, acc0.y);
                acc0.z = __builtin_fmaf(a0, wv.z, acc0.z);
                acc0.w = __builtin_fmaf(a0, wv.w, acc0.w);
                acc1.x = __builtin_fmaf(a1, wv.x, acc1.x);
                acc1.y = __builtin_fmaf(a1, wv.y, acc1.y);
                acc1.z = __builtin_fmaf(a1, wv.z, acc1.z);
                acc1.w = __builtin_fmaf(a1, wv.w, acc1.w);
                acc2.x = __builtin_fmaf(a2, wv.x, acc2.x);
                acc2.y = __builtin_fmaf(a2, wv.y, acc2.y);
                acc2.z = __builtin_fmaf(a2, wv.z, acc2.z);
                acc2.w = __builtin_fmaf(a2, wv.w, acc2.w);
                acc3.x = __builtin_fmaf(a3, wv.x, acc3.x);
                acc3.y = __builtin_fmaf(a3, wv.y, acc3.y);
                acc3.z = __builtin_fmaf(a3, wv.z, acc3.z);
                acc3.w = __builtin_fmaf(a3, wv.w, acc3.w);
            }

            float* base = partial + (size_t)ch * 16 * H1_;
            float* d0 = base + (size_t)(4 * wg + 0) * H1_ + j0;
            float* d1 = base + (size_t)(4 * wg + 1) * H1_ + j0;
            float* d2p = base + (size_t)(4 * wg + 2) * H1_ + j0;
            float* d3 = base + (size_t)(4 * wg + 3) * H1_ + j0;
            stf(d0 + 0, acc0.x); stf(d0 + 1, acc0.y); stf(d0 + 2, acc0.z); stf(d0 + 3, acc0.w);
            stf(d1 + 0, acc1.x); stf(d1 + 1, acc1.y); stf(d1 + 2, acc1.z); stf(d1 + 3, acc1.w);
            stf(d2p + 0, acc2.x); stf(d2p + 1, acc2.y); stf(d2p + 2, acc2.z); stf(d2p + 3, acc2.w);
            stf(d3 + 0, acc3.x); stf(d3 + 1, acc3.y); stf(d3 + 2, acc3.z); stf(d3 + 3, acc3.w);
        }
        post_flag(&fC[bx]);

    } else if (bx < NB_A + NB_D) {
        // ---- Phase D: reduce 256 chunks + bias + leaky -> h1T[col][16] ---
        wait_word(&done[2]);
        const int p = (bx - NB_A) * 256 + tid;   // b*H1 + col
        float s = 0.0f;
#pragma unroll 8
        for (int c = 0; c < 256; ++c) s += ldf(&partial[(size_t)c * (16 * H1_) + p]);
        const int col = p & (H1_ - 1);
        const int b   = p >> 10;
        s += b1[col];
        s = fmaxf(s, LEAKY_SLOPE * s);
        stf(&h1T[(size_t)col * 16 + b], s);
        post_flag(&fD[bx - NB_A]);

    } else if (bx < NB_A + NB_D + NB_E) {
        // ---- Phase E: L2 [16,1024]@[1024,512] + bias + leaky -> h2T ------
        wait_word(&done[3]);
        const int lane = tid & 63;
        const int w    = tid >> 6;
        const int eb   = bx - (NB_A + NB_D);   // [0,8)
        const int j    = eb * 64 + lane;

        float acc[16];
#pragma unroll
        for (int r = 0; r < 16; ++r) acc[r] = 0.0f;

        for (int ch = 0; ch < 8; ++ch) {       // 128 h1-rows per chunk
            __syncthreads();
#pragma unroll
            for (int j8 = 0; j8 < 8; ++j8) {
                int e = tid * 8 + j8;          // [0,2048)
                stage[e] = ldf(&h1T[ch * 2048 + e]);
            }
            __syncthreads();
            const int r0 = w * 32;
#pragma unroll 4
            for (int ii = 0; ii < 32; ++ii) {
                float wv = W2[(size_t)(ch * 128 + r0 + ii) * H2_ + j];
                const float4* Ar = (const float4*)&stage[(r0 + ii) * 16];
                float4 q0 = Ar[0], q1 = Ar[1], q2 = Ar[2], q3 = Ar[3];
                acc[0]  = __builtin_fmaf(q0.x, wv, acc[0]);
                acc[1]  = __builtin_fmaf(q0.y, wv, acc[1]);
                acc[2]  = __builtin_fmaf(q0.z, wv, acc[2]);
                acc[3]  = __builtin_fmaf(q0.w, wv, acc[3]);
                acc[4]  = __builtin_fmaf(q1.x, wv, acc[4]);
                acc[5]  = __builtin_fmaf(q1.y, wv, acc[5]);
                acc[6]  = __builtin_fmaf(q1.z, wv, acc[6]);
                acc[7]  = __builtin_fmaf(q1.w, wv, acc[7]);
                acc[8]  = __builtin_fmaf(q2.x, wv, acc[8]);
                acc[9]  = __builtin_fmaf(q2.y, wv, acc[9]);
                acc[10] = __builtin_fmaf(q2.z, wv, acc[10]);
                acc[11] = __builtin_fmaf(q2.w, wv, acc[11]);
                acc[12] = __builtin_fmaf(q3.x, wv, acc[12]);
                acc[13] = __builtin_fmaf(q3.y, wv, acc[13]);
                acc[14] = __builtin_fmaf(q3.z, wv, acc[14]);
                acc[15] = __builtin_fmaf(q3.w, wv, acc[15]);
            }
        }
        __syncthreads();
        if (w < 2) {
#pragma unroll
            for (int r = 0; r < 16; ++r) red[w][lane][r] = acc[r];
        }
        __syncthreads();
        if (w >= 2) {
#pragma unroll
            for (int r = 0; r < 16; ++r) red[w - 2][lane][r] += acc[r];
        }
        __syncthreads();
#pragma unroll
        for (int e = 0; e < 4; ++e) {
            int p  = tid * 4 + e;
            int cl = p >> 4;
            int bt = p & 15;
            float s = b2[eb * 64 + cl] + red[0][cl][bt] + red[1][cl][bt];
            s = fmaxf(s, LEAKY_SLOPE * s);
            stf(&h2T[((size_t)eb * 64 + cl) * 16 + bt], s);
        }
        post_flag(&fE[eb]);

    } else {
        // ---- aggregator (block 1099) + Phase F workers -------------------
        if (bx == NBLK - 1) {
            aggregate(fA, 1024, &done[0]);
            aggregate(fB, 256,  &done[1]);
            aggregate(fC, 1024, &done[2]);
            aggregate(fD, 64,   &done[3]);
            aggregate(fE, 8,    &done[4]);
        } else {
            wait_word(&done[4]);
        }
        // Phase F: L3 [16,512]@[512,256] + bias -> gfeat
        const int lane = tid & 63;
        const int w    = tid >> 6;
        const int fb   = bx - (NB_A + NB_D + NB_E);   // [0,4)
        const int j    = fb * 64 + lane;

        float acc[16];
#pragma unroll
        for (int r = 0; r < 16; ++r) acc[r] = 0.0f;

        for (int ch = 0; ch < 4; ++ch) {       // 128 h2-rows per chunk
            __syncthreads();
#pragma unroll
            for (int j8 = 0; j8 < 8; ++j8) {
                int e = tid * 8 + j8;
                stage[e] = ldf(&h2T[ch * 2048 + e]);
            }
            __syncthreads();
            const int r0 = w * 32;
#pragma unroll 4
            for (int ii = 0; ii < 32; ++ii) {
                float wv = W3[(size_t)(ch * 128 + r0 + ii) * OUT_ + j];
                const float4* Ar = (const float4*)&stage[(r0 + ii) * 16];
                float4 q0 = Ar[0], q1 = Ar[1], q2 = Ar[2], q3 = Ar[3];
                acc[0]  = __builtin_fmaf(q0.x, wv, acc[0]);
                acc[1]  = __builtin_fmaf(q0.y, wv, acc[1]);
                acc[2]  = __builtin_fmaf(q0.z, wv, acc[2]);
                acc[3]  = __builtin_fmaf(q0.w, wv, acc[3]);
                acc[4]  = __builtin_fmaf(q1.x, wv, acc[4]);
                acc[5]  = __builtin_fmaf(q1.y, wv, acc[5]);
                acc[6]  = __builtin_fmaf(q1.z, wv, acc[6]);
                acc[7]  = __builtin_fmaf(q1.w, wv, acc[7]);
                acc[8]  = __builtin_fmaf(q2.x, wv, acc[8]);
                acc[9]  = __builtin_fmaf(q2.y, wv, acc[9]);
                acc[10] = __builtin_fmaf(q2.z, wv, acc[10]);
                acc[11] = __builtin_fmaf(q2.w, wv, acc[11]);
                acc[12] = __builtin_fmaf(q3.x, wv, acc[12]);
                acc[13] = __builtin_fmaf(q3.y, wv, acc[13]);
                acc[14] = __builtin_fmaf(q3.z, wv, acc[14]);
                acc[15] = __builtin_fmaf(q3.w, wv, acc[15]);
            }
        }
        __syncthreads();
        if (w < 2) {
#pragma unroll
            for (int r = 0; r < 16; ++r) red[w][lane][r] = acc[r];
        }
        __syncthreads();
        if (w >= 2) {
#pragma unroll
            for (int r = 0; r < 16; ++r) red[w - 2][lane][r] += acc[r];
        }
        __syncthreads();
#pragma unroll
        for (int e = 0; e < 4; ++e) {
            int p  = tid * 4 + e;
            int cl = p >> 4;
            int bt = p & 15;
            float s = b3[fb * 64 + cl] + red[0][cl][bt] + red[1][cl][bt];
            gfeat[(size_t)bt * OUT_ + fb * 64 + cl] = s;   // final output
        }
    }
}

// -------------------------------------------------------------------------
extern "C" void kernel_launch(void* const* d_in, const int* in_sizes, int n_in,
                              void* d_out, int out_size, void* d_ws, size_t ws_size,
                              hipStream_t stream)
{
    const float* pc    = (const float*)d_in[0];
    const float* basis = (const float*)d_in[1];
    const float* W1    = (const float*)d_in[2];
    const float* b1    = (const float*)d_in[3];
    const float* W2    = (const float*)d_in[4];
    const float* b2    = (const float*)d_in[5];
    const float* W3    = (const float*)d_in[6];
    const float* b3    = (const float*)d_in[7];

    float* out   = (float*)d_out;
    float* gfeat = out;                 // [16][256]
    float* bps   = out + B_ * OUT_;     // [16][16384]

    char* ws = (char*)d_ws;
    unsigned long long* part_enc = (unsigned long long*)ws;           // 16MB
    float* partial = (float*)(ws + (size_t)16 * 1024 * 1024);         // 16MB
    float* h1T     = (float*)(ws + (size_t)32 * 1024 * 1024);         // 64KB
    float* h2T     = (float*)(ws + (size_t)32 * 1024 * 1024 + 64 * 1024);  // 32KB
    unsigned* flags = (unsigned*)(ws + (size_t)33 * 1024 * 1024);     // ~9.5KB

    pipeline<<<NBLK, 256, 0, stream>>>(
        pc, basis, W1, b1, W2, b2, W3, b3,
        gfeat, bps, part_enc, partial, h1T, h2T, flags);
}